// Round 18
// baseline (592.404 us; speedup 1.0000x reference)
//
#include <hip/hip_runtime.h>
#include <hip/hip_bf16.h>
#include <math.h>

typedef __hip_bfloat16 bf16;
typedef short bf16x8 __attribute__((ext_vector_type(8)));
typedef float f32x4 __attribute__((ext_vector_type(4)));

#define NB 4
#define HH 128
#define WWID 128
#define CC 192
#define NPB (HH*WWID)      // 16384 tokens per batch
#define NT (NB*NPB)        // 65536 total tokens
#define NHEADS 6
#define HD 32
#define NTOK 64
#define RDIM 10
#define DTD 64
#define MLPH 384
#define CHF (MLPH+DTD)     // 448

__device__ __forceinline__ float b2f(bf16 v){ return __bfloat162float(v); }
__device__ __forceinline__ bf16  f2b(float v){ return __float2bfloat16(v); }
__device__ __forceinline__ float bfu(unsigned short u){ return __uint_as_float(((unsigned)u)<<16); }
__device__ __forceinline__ float geluf(float v){ return 0.5f*v*(1.0f+erff(v*0.70710678118654752f)); }
__device__ __forceinline__ int rg3(int v){ return v<112?0:(v<120?1:2); }

__device__ __forceinline__ void gload16(const void* g, void* l){
  __builtin_amdgcn_global_load_lds((const __attribute__((address_space(1))) unsigned*)g,
                                   (__attribute__((address_space(3))) unsigned*)l, 16, 0, 0);
}

__device__ __forceinline__ float wsumf(float v){
  #pragma unroll
  for (int m=32;m>0;m>>=1) v += __shfl_xor(v,m);
  return v;
}

__global__ void k_sentinel(float* out, int n, float v){
  int i = blockIdx.x*256+threadIdx.x;
  if (i<n) out[i]=v;
}

// ---------------- weight converters ----------------
__global__ __launch_bounds__(256) void k_wt(const float* __restrict__ W, bf16* __restrict__ Wt, int K, int N){
  int i = blockIdx.x*256+threadIdx.x;
  if (i < K*N){ int n = i / K, k = i - n*K; Wt[i] = f2b(W[(size_t)k*N + n]); }
}

// gw[c][r] = n1g[c]*wq[c][r];  S12[r]=S1_r, S12[10+r]=S2_r+wqb[r]  (f64, for k_sim)
__global__ __launch_bounds__(256) void k_gw(const float* __restrict__ n1g, const float* __restrict__ n1b,
                                            const float* __restrict__ wq, const float* __restrict__ wqb,
                                            double* __restrict__ gw, double* __restrict__ S12){
  int ti=threadIdx.x;
  for (int i=ti;i<1920;i+=256){
    int c=i/10;
    gw[i]=(double)n1g[c]*(double)wq[i];
  }
  if (ti<10){
    double s1=0.0,s2=0.0;
    for (int c=0;c<192;c++){
      double w=(double)wq[c*10+ti];
      s1=fma((double)n1g[c],w,s1);
      s2=fma((double)n1b[c],w,s2);
    }
    S12[ti]=s1; S12[10+ti]=s2+(double)wqb[ti];
  }
}

// ---------------- tiny dict projections ----------------
__global__ __launch_bounds__(64) void k_kn(const float* __restrict__ td, const float* __restrict__ wk,
                                           const float* __restrict__ wkb, double* __restrict__ kn){
  int t = blockIdx.x*64+threadIdx.x;            // 0..255 = (b,m)
  double kk[10]; double sq=0.0;
  const float* tr = td + (size_t)t*CC;
  #pragma unroll
  for (int r=0;r<10;r++) kk[r]=(double)wkb[r];
  for (int k=0;k<CC;k++){
    double tv=(double)tr[k];
    #pragma unroll
    for (int r=0;r<10;r++) kk[r] += tv*(double)wk[k*10+r];
  }
  #pragma unroll
  for (int r=0;r<10;r++) sq += kk[r]*kk[r];
  double inv = 1.0/fmax(sqrt(sq),1e-12);
  #pragma unroll
  for (int r=0;r<10;r++) kn[t*10+r]=kk[r]*inv;
}

__global__ __launch_bounds__(256) void k_v(const float* __restrict__ td, const float* __restrict__ wv,
                                           const float* __restrict__ wvb, float* __restrict__ vb){
  int idx = blockIdx.x*256+threadIdx.x;         // < 4*64*192
  int c = idx % CC; int bm = idx / CC;
  const float* tr = td + (size_t)bm*CC;
  float a = wvb[c];
  for (int k=0;k<CC;k++) a = fmaf(tr[k], wv[(size_t)k*CC+c], a);
  vb[idx] = a;
}

__global__ __launch_bounds__(256) void k_tdf(const float* __restrict__ td, const float* __restrict__ w,
                                             const float* __restrict__ bb, float* __restrict__ tdf){
  int idx = blockIdx.x*256+threadIdx.x;         // < 4*64*64
  int d = idx & 63; int bm = idx >> 6;
  const float* tr = td + (size_t)bm*CC;
  float a = bb[d];
  for (int k=0;k<CC;k++) a = fmaf(tr[k], w[(size_t)k*64+d], a);
  tdf[idx] = a;
}

// rpbq[h][q][k] = rpbt[rpi[q*256+k]*6+h]
__global__ __launch_bounds__(256) void k_rpbq(const int* __restrict__ rpi, const float* __restrict__ rpbt,
                                              bf16* __restrict__ rpbq){
  int idx = blockIdx.x*256+threadIdx.x;         // < 6*65536
  int h = idx>>16; int qk = idx&65535;
  rpbq[idx] = f2b(rpbt[rpi[qk]*6 + h]);
}

// ---------------- sim / argmax v5: 32 tok/block, thread=(tok,subslice), 12 f64 chains ----------------
__global__ __launch_bounds__(256) void k_sim(const float* __restrict__ x, const double* __restrict__ gw,
                                             const double* __restrict__ S12, const double* __restrict__ kn,
                                             const float* __restrict__ atds,
                                             float* __restrict__ sim, int* __restrict__ tkid){
  __shared__ double gws[1920];                   // 15.4KB
  __shared__ double S12s[20];
  __shared__ double ql[32][10];                  // 2.5KB
  int ti = threadIdx.x;
  int blk = blockIdx.x;                          // NT/32 = 2048 blocks
  for (int i=ti;i<1920;i+=256) gws[i]=gw[i];
  if (ti<20) S12s[ti]=S12[ti];
  __syncthreads();
  {
    int tok = ti>>3, sub = ti&7;
    const float* xr = x + ((size_t)(blk*32+tok))*192 + sub*24;
    float xv[24];
    #pragma unroll
    for (int q4=0;q4<6;q4++) *(float4*)(xv+q4*4) = *(const float4*)(xr+q4*4);
    double acc[10]; double s=0.0, s2=0.0;
    #pragma unroll
    for (int r=0;r<10;r++) acc[r]=0.0;
    #pragma unroll
    for (int c=0;c<24;c++){
      double v=(double)xv[c];
      s+=v; s2=fma(v,v,s2);
      const double* gr = gws + (sub*24+c)*10;
      #pragma unroll
      for (int r=0;r<10;r++) acc[r]=fma(v,gr[r],acc[r]);
    }
    #pragma unroll
    for (int m=1;m<8;m<<=1){
      s+=__shfl_xor(s,m); s2+=__shfl_xor(s2,m);
      #pragma unroll
      for (int r=0;r<10;r++) acc[r]+=__shfl_xor(acc[r],m);
    }
    if (sub==0){
      double mu=s*(1.0/192.0);
      double var=s2*(1.0/192.0)-mu*mu;
      double rs=1.0/sqrt(var+1e-5);
      #pragma unroll
      for (int r=0;r<10;r++) ql[tok][r]=rs*(acc[r]-mu*S12s[r])+S12s[10+r];
    }
  }
  __syncthreads();
  int wave = ti>>6, lane = ti&63;
  int b = blk>>9;                                // 512 blocks per batch
  double kr[10];
  #pragma unroll
  for (int r2=0;r2<10;r2++) kr[r2]=kn[((size_t)(b*64+lane))*10+r2];
  double asd=fmin(fmax((double)atds[0],0.0),3.0);
  double scl=1.0+asd*4.1588830833596715;         // 1 + clip*ln(64)
  for (int tk=wave; tk<32; tk+=4){
    double dot=0.0, sq=0.0;
    #pragma unroll
    for (int r2=0;r2<10;r2++){
      double qv=ql[tk][r2];
      dot=fma(qv,kr[r2],dot);
      sq =fma(qv,qv,sq);
    }
    dot *= 1.0/fmax(sqrt(sq),1e-12);
    double bv=dot; int bi=lane;
    #pragma unroll
    for (int m2=32;m2>0;m2>>=1){
      double ov=__shfl_xor(bv,m2); int oi=__shfl_xor(bi,m2);
      if (ov>bv || (ov==bv && oi<bi)){ bv=ov; bi=oi; }
    }
    int tokg = blk*32+tk;
    if (lane==0) tkid[tokg]=bi;
    float t=(float)(dot*scl);
    float pp=__expf(t);
    float ssf=pp;
    #pragma unroll
    for (int m2=32;m2>0;m2>>=1) ssf+=__shfl_xor(ssf,m2);
    sim[(size_t)tokg*64+lane]=pp/ssf;
  }
}

// ---------------- MFMA GEMM: C[M][N] = A[M][K] @ Wt^T, tile 64x64, 4 waves ----------------
// LNIN: 0=bf16 A as-is; 1=f32 input + fused LayerNorm; 2=bf16 input + fused LayerNorm.
// Staging: async global_load_lds for W (and A when LNIN==0 && KC/8%8==0); LN path stages A
// through registers with the same XOR-swizzled layout. Read side: LDS[r][u^(r&7)]=G[r][u].
// OUTMODE 0: bf16 out (+ACT gelu). 2: f32 out = bf16(aux)[o] + v.
// 3: xacc-init = f32 x(aux)[perm] + v (window-reverse perm).  4: xacc += v (sidx perm, RMW).
template<int K, int KC, int NS, int ACT, int OUTMODE, int LNIN>
__global__ __launch_bounds__(256) void k_mm(const bf16* __restrict__ A, const bf16* __restrict__ Wt,
                                            const float* __restrict__ bias, const void* __restrict__ aux,
                                            void* __restrict__ outp,
                                            const void* __restrict__ lnx, const float* __restrict__ lng,
                                            const float* __restrict__ lnb){
  __shared__ __align__(16) char As[64*KC*2];
  __shared__ __align__(16) char Ws[64*KC*2];
  int row0 = blockIdx.x*64, n0 = blockIdx.y*64;
  int ti = threadIdx.x;
  int wave = ti>>6, lane = ti&63, g = lane>>4, l15 = lane&15;
  f32x4 acc[4];
  #pragma unroll
  for (int mt=0;mt<4;mt++){ f32x4 z={0.f,0.f,0.f,0.f}; acc[mt]=z; }
  const int KC8 = KC/8;
  for (int c0=0; c0<K; c0+=KC){
    if (c0) __syncthreads();
    if constexpr (LNIN != 0){
      // fused-LN A staging (K==KC==192): 4 threads/row, 48 ch each, in-wave reduce
      static_assert(K==192 && KC==192, "LNIN requires K=KC=192");
      int r = ti>>2, q4 = ti&3;
      float xv[48];
      if constexpr (LNIN==1){
        const float* xr = (const float*)lnx + (size_t)(row0+r)*192 + q4*48;
        #pragma unroll
        for (int i=0;i<12;i++) *(float4*)(xv+i*4) = *(const float4*)(xr+i*4);
      } else {
        const bf16* xr = (const bf16*)lnx + (size_t)(row0+r)*192 + q4*48;
        #pragma unroll
        for (int i=0;i<6;i++){
          bf16x8 v8 = *(const bf16x8*)(xr+i*8);
          #pragma unroll
          for (int c=0;c<8;c++) xv[i*8+c]=bfu((unsigned short)v8[c]);
        }
      }
      float s=0.f, s2=0.f;
      #pragma unroll
      for (int c=0;c<48;c++){ s+=xv[c]; s2=fmaf(xv[c],xv[c],s2); }
      s  += __shfl_xor(s,1);  s2 += __shfl_xor(s2,1);
      s  += __shfl_xor(s,2);  s2 += __shfl_xor(s2,2);
      float mu = s*(1.0f/192.0f);
      float var = s2*(1.0f/192.0f) - mu*mu;
      float rs = rsqrtf(var+1e-5f);
      #pragma unroll
      for (int i=0;i<6;i++){
        int ch0 = q4*48 + i*8;
        float4 g0 = *(const float4*)(lng+ch0), g1 = *(const float4*)(lng+ch0+4);
        float4 b0 = *(const float4*)(lnb+ch0), b1 = *(const float4*)(lnb+ch0+4);
        float gg[8]={g0.x,g0.y,g0.z,g0.w,g1.x,g1.y,g1.z,g1.w};
        float bbv[8]={b0.x,b0.y,b0.z,b0.w,b1.x,b1.y,b1.z,b1.w};
        bf16 tmp[8];
        #pragma unroll
        for (int c=0;c<8;c++) tmp[c]=f2b((xv[i*8+c]-mu)*rs*gg[c]+bbv[c]);
        int kc = q4*6 + i;
        *(uint4*)(As + ((r*(KC*2) + kc*16) ^ ((r&7)<<4))) = *(const uint4*)tmp;
      }
      // W async
      for (int u0 = wave*64; u0 < 64*KC8; u0 += 256){
        int u = u0 + lane;
        int rr = u/KC8, kc = u - rr*KC8;
        int kcs = kc ^ (rr&7);
        gload16(Wt + (size_t)(n0+rr)*K + (kcs<<3), Ws + (size_t)u0*16);
      }
    } else if constexpr ((KC/8)%8==0){
      // async direct-to-LDS: dest linear (wave-uniform base + lane*16), src unit pre-swizzled
      for (int u0 = wave*64; u0 < 64*KC8; u0 += 256){
        int u = u0 + lane;
        int r = u/KC8, kc = u - r*KC8;
        int kcs = kc ^ (r&7);                    // stays in [0,KC8) since KC8 % 8 == 0
        gload16(A  + (size_t)(row0+r)*K + c0 + (kcs<<3), As + (size_t)u0*16);
        gload16(Wt + (size_t)(n0+r)*K  + c0 + (kcs<<3), Ws + (size_t)u0*16);
      }
    } else {
      for (int u=ti; u<64*KC8; u+=256){
        int r = u/KC8, kc = u-r*KC8;
        uint4 va = *(const uint4*)(A  + (size_t)(row0+r)*K + c0 + kc*8);
        *(uint4*)(As + ((r*(KC*2) + kc*16) ^ ((r&7)<<4))) = va;
        uint4 vw = *(const uint4*)(Wt + (size_t)(n0+r)*K + c0 + kc*8);
        *(uint4*)(Ws + ((r*(KC*2) + kc*16) ^ ((r&7)<<4))) = vw;
      }
    }
    __syncthreads();
    #pragma unroll
    for (int ks=0; ks<KC/32; ks++){
      int rw = wave*16 + l15;
      bf16x8 bfr = *(const bf16x8*)(Ws + ((rw*(KC*2) + ks*64 + g*16) ^ ((rw&7)<<4)));
      #pragma unroll
      for (int mt=0;mt<4;mt++){
        int ra = mt*16 + l15;
        bf16x8 af = *(const bf16x8*)(As + ((ra*(KC*2) + ks*64 + g*16) ^ ((ra&7)<<4)));
        acc[mt] = __builtin_amdgcn_mfma_f32_16x16x32_bf16(af, bfr, acc[mt], 0,0,0);
      }
    }
  }
  int col = n0 + wave*16 + l15;
  float bb = bias[col];
  #pragma unroll
  for (int mt=0;mt<4;mt++){
    #pragma unroll
    for (int j=0;j<4;j++){
      int row = row0 + mt*16 + g*4 + j;
      float v = acc[mt][j] + bb;
      if (OUTMODE==0){
        ((bf16*)outp)[(size_t)row*NS + col] = f2b(ACT ? geluf(v) : v);
      } else if (OUTMODE==2){
        size_t o = (size_t)row*NS + col;
        ((float*)outp)[o] = b2f(((const bf16*)aux)[o]) + v;
      } else if (OUTMODE==3){
        int win=row>>8, tii=row&255;
        int b=win>>6, wloc=win&63;
        int wy=wloc>>3, wx=wloc&7, tyy=tii>>4, txx=tii&15;
        int oy=(wy*16+tyy+8)&127, ox=(wx*16+txx+8)&127;
        size_t o=((size_t)(b*NPB + oy*128 + ox))*NS + col;
        ((bf16*)outp)[o] = f2b(((const float*)aux)[o] + v);
      } else {
        int orow=(row & ~(NPB-1)) + ((const int*)aux)[row];
        size_t o=(size_t)orow*NS + col;
        bf16* xo=(bf16*)outp;
        xo[o] = f2b(b2f(xo[o]) + v);
      }
    }
  }
}

// ---------------- scalar GEMM core (kept for xatd) ----------------
__device__ __forceinline__ float ldw(const bf16* p, size_t i){ return __bfloat162float(p[i]); }
__device__ __forceinline__ float ldw(const float* p, size_t i){ return p[i]; }

template<int KD, int CB, typename WT>
__device__ __forceinline__ void gemm_core(const float (*As)[KD], const WT* __restrict__ W, int N, float (&acc)[8][CB]){
  int tid = threadIdx.x;
  for (int k=0;k<KD;k+=4){
    float w0[CB],w1[CB],w2[CB],w3[CB];
    #pragma unroll
    for (int j=0;j<CB;j++){
      int c = tid + 64*j;
      w0[j]=ldw(W,(size_t)(k+0)*N+c);
      w1[j]=ldw(W,(size_t)(k+1)*N+c);
      w2[j]=ldw(W,(size_t)(k+2)*N+c);
      w3[j]=ldw(W,(size_t)(k+3)*N+c);
    }
    #pragma unroll
    for (int r=0;r<8;r++){
      float4 a = *reinterpret_cast<const float4*>(&As[r][k]);
      #pragma unroll
      for (int j=0;j<CB;j++)
        acc[r][j]=fmaf(a.x,w0[j],fmaf(a.y,w1[j],fmaf(a.z,w2[j],fmaf(a.w,w3[j],acc[r][j]))));
    }
  }
}

// xacc += sim @ v
__global__ __launch_bounds__(64) void k_xatd(const float* __restrict__ sim, const float* __restrict__ vb,
                                             bf16* __restrict__ xacc){
  __shared__ __align__(16) float As[8][64];
  int row0=blockIdx.x*8;
  for (int idx=threadIdx.x; idx<8*64; idx+=64){
    int r=idx>>6, k=idx&63;
    As[r][k]=sim[(size_t)(row0+r)*64+k];
  }
  __syncthreads();
  float acc[8][3]={};
  const float* Wv = vb + (size_t)(row0>>14)*64*CC;
  gemm_core<64,3>(As, Wv, CC, acc);
  int tid=threadIdx.x;
  #pragma unroll
  for (int j=0;j<3;j++){
    int c=tid+64*j;
    #pragma unroll
    for (int r=0;r<8;r++){
      size_t o=(size_t)(row0+r)*CC+c;
      xacc[o]=f2b(b2f(xacc[o])+acc[r][j]);
    }
  }
}

__global__ __launch_bounds__(256) void k_tdgather(const float* __restrict__ tdf, const int* __restrict__ tkid,
                                                  bf16* __restrict__ xc){
  int idx = blockIdx.x*256+threadIdx.x;   // NT*64
  int d = idx & 63; int tok = idx >> 6;
  int b = tok >> 14;
  int m = tkid[tok];
  xc[(size_t)tok*CHF + MLPH + d] = f2b(tdf[((size_t)((b<<6)+m))*64 + d]);
}

// ---------------- stable counting sort of tk_id ----------------
__global__ __launch_bounds__(256) void k_hist(const int* __restrict__ tkid, int* __restrict__ chist){
  __shared__ int h[64];
  int b = blockIdx.x>>6, ch = blockIdx.x&63;
  if (threadIdx.x<64) h[threadIdx.x]=0;
  __syncthreads();
  int v = tkid[b*NPB + ch*256 + threadIdx.x];
  atomicAdd(&h[v],1);
  __syncthreads();
  if (threadIdx.x<64) chist[(size_t)blockIdx.x*64 + threadIdx.x] = h[threadIdx.x];
}

__global__ __launch_bounds__(64) void k_scan(const int* __restrict__ chist, int* __restrict__ coff,
                                             int* __restrict__ bstart){
  int b = blockIdx.x; int v = threadIdx.x;
  __shared__ int tot[64], bs[64];
  int s=0;
  for (int ch=0; ch<64; ch++){
    coff[((size_t)(b*64+ch))*64+v] = s;
    s += chist[((size_t)(b*64+ch))*64+v];
  }
  tot[v]=s;
  __syncthreads();
  if (v==0){ int run=0; for (int u=0;u<64;u++){ bs[u]=run; run+=tot[u]; } }
  __syncthreads();
  bstart[b*64+v] = bs[v];
}

__global__ __launch_bounds__(256) void k_place(const int* __restrict__ tkid, const int* __restrict__ coff,
                                               const int* __restrict__ bstart, int* __restrict__ sidx){
  __shared__ int vals[256];
  int b = blockIdx.x>>6, ch = blockIdx.x&63;
  int tid = threadIdx.x;
  int tok = ch*256 + tid;
  int v = tkid[b*NPB + tok];
  vals[tid]=v;
  __syncthreads();
  int lr=0;
  for (int j=0;j<tid;j++) lr += (vals[j]==v);
  int pos = bstart[b*64+v] + coff[((size_t)(b*64+ch))*64+v] + lr;
  sidx[b*NPB + pos] = tok;
}

// ---------------- AC_MSA grouped attention (MFMA flash, fixed-max softmax) ----------------
__global__ __launch_bounds__(256,4) void k_acattn(const bf16* __restrict__ qkv, const int* __restrict__ sidx,
                                                  bf16* __restrict__ yg){
  __shared__ bf16 Kl[128*32];
  __shared__ bf16 Vt[32*128];
  __shared__ bf16 Ps[4][16*32];
  int bid=blockIdx.x;
  int h = bid % NHEADS; int gg = (bid/NHEADS) & 127; int b = bid/(NHEADS*128);
  int ti = threadIdx.x;
  if (ti < 128){
    int srow = b*NPB + sidx[b*NPB + gg*128 + ti];
    const bf16* src = qkv + (size_t)srow*576 + 192 + h*32;
    const uint4* s4 = (const uint4*)src;
    char* kb = (char*)Kl;
    #pragma unroll
    for (int w=0;w<4;w++) *(uint4*)(kb + ((ti*64 + w*16) ^ ((ti&7)<<4))) = s4[w];
    const bf16* vsrc = src + 192;
    char* vbp = (char*)Vt;
    #pragma unroll
    for (int d=0;d<32;d++) *(bf16*)(vbp + ((d*256 + ti*2) ^ ((d&7)<<4))) = vsrc[d];
  }
  __syncthreads();
  int wave=ti>>6, lane=ti&63, g=lane>>4, l15=lane&15;
  bf16x8 qf[2];
  #pragma unroll
  for (int qt=0;qt<2;qt++){
    int q = wave*32 + qt*16 + l15;
    int srow = b*NPB + sidx[b*NPB + gg*128 + q];
    qf[qt] = *(const bf16x8*)(qkv + (size_t)srow*576 + h*32 + g*8);
  }
  f32x4 O[2][2]; float lsp[2][4];
  #pragma unroll
  for (int qt=0;qt<2;qt++){
    #pragma unroll
    for (int dt=0;dt<2;dt++){ f32x4 z={0.f,0.f,0.f,0.f}; O[qt][dt]=z; }
    #pragma unroll
    for (int j=0;j<4;j++) lsp[qt][j]=0.f;
  }
  const float rsc=0.17677669529663687f;
  const char* kb=(const char*)Kl; const char* vbp=(const char*)Vt;
  for (int st=0; st<4; st++){
    int r0=st*32+l15, r1=st*32+16+l15;
    bf16x8 kf0 = *(const bf16x8*)(kb + ((r0*64 + g*16) ^ ((r0&7)<<4)));
    bf16x8 kf1 = *(const bf16x8*)(kb + ((r1*64 + g*16) ^ ((r1&7)<<4)));
    int d0=l15, d1=16+l15;
    bf16x8 vf0 = *(const bf16x8*)(vbp + ((d0*256 + st*64 + g*16) ^ ((d0&7)<<4)));
    bf16x8 vf1 = *(const bf16x8*)(vbp + ((d1*256 + st*64 + g*16) ^ ((d1&7)<<4)));
    #pragma unroll
    for (int qt=0;qt<2;qt++){
      f32x4 z={0.f,0.f,0.f,0.f};
      f32x4 s0 = __builtin_amdgcn_mfma_f32_16x16x32_bf16(qf[qt], kf0, z, 0,0,0);
      f32x4 s1 = __builtin_amdgcn_mfma_f32_16x16x32_bf16(qf[qt], kf1, z, 0,0,0);
      float p0[4],p1[4];
      char* pb=(char*)Ps[wave];
      #pragma unroll
      for (int j=0;j<4;j++){
        p0[j]=__expf(fminf(s0[j]*rsc,80.f));
        p1[j]=__expf(fminf(s1[j]*rsc,80.f));
        lsp[qt][j]+=p0[j]+p1[j];
        int q=g*4+j;
        *(bf16*)(pb + ((q*64 + l15*2) ^ ((q&7)<<4)))      = f2b(p0[j]);
        *(bf16*)(pb + ((q*64 + 32 + l15*2) ^ ((q&7)<<4))) = f2b(p1[j]);
      }
      bf16x8 pa = *(const bf16x8*)((const char*)Ps[wave] + ((l15*64 + g*16) ^ ((l15&7)<<4)));
      O[qt][0]=__builtin_amdgcn_mfma_f32_16x16x32_bf16(pa, vf0, O[qt][0], 0,0,0);
      O[qt][1]=__builtin_amdgcn_mfma_f32_16x16x32_bf16(pa, vf1, O[qt][1], 0,0,0);
    }
  }
  #pragma unroll
  for (int qt=0;qt<2;qt++){
    #pragma unroll
    for (int msk=1; msk<16; msk<<=1){
      #pragma unroll
      for (int j=0;j<4;j++) lsp[qt][j]+=__shfl_xor(lsp[qt][j],msk);
    }
    #pragma unroll
    for (int j=0;j<4;j++){
      float inv=1.0f/lsp[qt][j];
      int q = wave*32 + qt*16 + g*4 + j;
      bf16* yo = yg + ((size_t)(b*NPB + gg*128 + q))*CC + h*32;
      yo[l15]    = f2b(O[qt][0][j]*inv);
      yo[16+l15] = f2b(O[qt][1][j]*inv);
    }
  }
}

// ---------------- shifted-window attention (MFMA flash, fixed-max softmax) ----------------
__global__ __launch_bounds__(256,3) void k_winattn(const bf16* __restrict__ qkv, const bf16* __restrict__ rpbq,
                                                   bf16* __restrict__ yw){
  __shared__ bf16 Kl[256*32];
  __shared__ bf16 Vt[32*256];
  __shared__ bf16 Ps[4][16*32];
  int bid = blockIdx.x;
  int h = bid % NHEADS; int win = bid / NHEADS;
  int b = win >> 6; int wloc = win & 63;
  int wy = wloc >> 3, wx = wloc & 7;
  int ti = threadIdx.x;
  {
    int ty=ti>>4, tx=ti&15;
    int oy=(wy*16+ty+8)&127, ox=(wx*16+tx+8)&127;
    const bf16* src = qkv + (size_t)(b*NPB+oy*128+ox)*576 + 192 + h*32;
    const uint4* s4 = (const uint4*)src;
    char* kb = (char*)Kl;
    #pragma unroll
    for (int w=0;w<4;w++) *(uint4*)(kb + ((ti*64 + w*16) ^ ((ti&7)<<4))) = s4[w];
    const bf16* vsrc = src + 192;
    char* vbp = (char*)Vt;
    #pragma unroll
    for (int d=0;d<32;d++) *(bf16*)(vbp + ((d*512 + ti*2) ^ ((d&7)<<4))) = vsrc[d];
  }
  __syncthreads();
  int wave=ti>>6, lane=ti&63, g=lane>>4, l15=lane&15;
  bf16x8 qf[4];
  #pragma unroll
  for (int qt=0;qt<4;qt++){
    int ty=wave*4+qt, tx=l15;
    int oy=(wy*16+ty+8)&127, ox=(wx*16+tx+8)&127;
    qf[qt] = *(const bf16x8*)(qkv + (size_t)(b*NPB+oy*128+ox)*576 + h*32 + g*8);
  }
  f32x4 O[4][2]; float lsp[4][4];
  #pragma unroll
  for (int qt=0;qt<4;qt++){
    #pragma unroll
    for (int dt=0;dt<2;dt++){ f32x4 z={0.f,0.f,0.f,0.f}; O[qt][dt]=z; }
    #pragma unroll
    for (int j=0;j<4;j++) lsp[qt][j]=0.f;
  }
  const float rsc=0.17677669529663687f;
  int rxk = rg3(wx*16+l15);
  int rxq[4], ryq[4];
  #pragma unroll
  for (int j=0;j<4;j++) rxq[j]=rg3(wx*16+g*4+j);
  #pragma unroll
  for (int qt=0;qt<4;qt++) ryq[qt]=rg3(wy*16+wave*4+qt);
  const char* kb=(const char*)Kl; const char* vbp=(const char*)Vt;
  for (int st=0; st<8; st++){
    int r0=st*32+l15, r1=st*32+16+l15;
    bf16x8 kf0 = *(const bf16x8*)(kb + ((r0*64 + g*16) ^ ((r0&7)<<4)));
    bf16x8 kf1 = *(const bf16x8*)(kb + ((r1*64 + g*16) ^ ((r1&7)<<4)));
    int d0=l15, d1=16+l15;
    bf16x8 vf0 = *(const bf16x8*)(vbp + ((d0*512 + st*64 + g*16) ^ ((d0&7)<<4)));
    bf16x8 vf1 = *(const bf16x8*)(vbp + ((d1*512 + st*64 + g*16) ^ ((d1&7)<<4)));
    int rk0 = rg3(wy*16+st*2)*3   + rxk;
    int rk1 = rg3(wy*16+st*2+1)*3 + rxk;
    #pragma unroll
    for (int qt=0;qt<4;qt++){
      f32x4 z={0.f,0.f,0.f,0.f};
      f32x4 s0 = __builtin_amdgcn_mfma_f32_16x16x32_bf16(qf[qt], kf0, z, 0,0,0);
      f32x4 s1 = __builtin_amdgcn_mfma_f32_16x16x32_bf16(qf[qt], kf1, z, 0,0,0);
      int qr0 = wave*64 + qt*16 + g*4;
      float p0[4],p1[4];
      char* pb=(char*)Ps[wave];
      #pragma unroll
      for (int j=0;j<4;j++){
        const bf16* rb = rpbq + (((size_t)h*256 + qr0 + j)<<8) + st*32;
        int rq = ryq[qt]*3 + rxq[j];
        float b0 = b2f(rb[l15])    + (rq!=rk0 ? -100.f : 0.f);
        float b1 = b2f(rb[16+l15]) + (rq!=rk1 ? -100.f : 0.f);
        p0[j]=__expf(fminf(fmaf(s0[j],rsc,b0),80.f));
        p1[j]=__expf(fminf(fmaf(s1[j],rsc,b1),80.f));
        lsp[qt][j]+=p0[j]+p1[j];
        int q=g*4+j;
        *(bf16*)(pb + ((q*64 + l15*2) ^ ((q&7)<<4)))      = f2b(p0[j]);
        *(bf16*)(pb + ((q*64 + 32 + l15*2) ^ ((q&7)<<4))) = f2b(p1[j]);
      }
      bf16x8 pa = *(const bf16x8*)((const char*)Ps[wave] + ((l15*64 + g*16) ^ ((l15&7)<<4)));
      O[qt][0]=__builtin_amdgcn_mfma_f32_16x16x32_bf16(pa, vf0, O[qt][0], 0,0,0);
      O[qt][1]=__builtin_amdgcn_mfma_f32_16x16x32_bf16(pa, vf1, O[qt][1], 0,0,0);
    }
  }
  #pragma unroll
  for (int qt=0;qt<4;qt++){
    #pragma unroll
    for (int msk=1; msk<16; msk<<=1){
      #pragma unroll
      for (int j=0;j<4;j++) lsp[qt][j]+=__shfl_xor(lsp[qt][j],msk);
    }
    #pragma unroll
    for (int j=0;j<4;j++){
      float inv=1.0f/lsp[qt][j];
      int q = wave*64 + qt*16 + g*4 + j;
      bf16* yo = yw + ((size_t)win*256 + q)*CC + h*32;
      yo[l15]    = f2b(O[qt][0][j]*inv);
      yo[16+l15] = f2b(O[qt][1][j]*inv);
    }
  }
}

// ---------------- depthwise conv v3 (256,4 known-good): 4 px/thread, f32 weights, 32-bit addr ----------------
__global__ __launch_bounds__(256,4) void k_dw(const bf16* __restrict__ xc, const float* __restrict__ dww,
                                              const float* __restrict__ dwb, bf16* __restrict__ sv){
  int tid = blockIdx.x*256 + threadIdx.x;       // < 16384*56 = 917504
  int ch8 = tid % 56; int pt = tid / 56;
  int x0 = (pt & 31)*4; int yq = (pt>>5)&127; int b = pt>>12;
  float acc[4][8];
  #pragma unroll
  for (int p=0;p<4;p++)
    #pragma unroll
    for (int c=0;c<8;c++) acc[p][c]=0.f;
  unsigned choff = (unsigned)ch8*8;
  const float* wp = dww + choff;
  #pragma unroll
  for (int dy=0;dy<5;dy++){
    int yy = yq+dy-2;
    if ((unsigned)yy>127u) continue;
    float4 w0[5], w1[5];
    #pragma unroll
    for (int dx=0;dx<5;dx++){
      w0[dx] = *(const float4*)(wp + (dy*5+dx)*CHF);
      w1[dx] = *(const float4*)(wp + (dy*5+dx)*CHF + 4);
    }
    unsigned rowoff = ((unsigned)(b<<14) + ((unsigned)yy<<7))*CHF + choff;
    #pragma unroll
    for (int j=0;j<8;j++){
      int ox = x0-2+j;
      if ((unsigned)ox>127u) continue;
      uint4 v = *(const uint4*)(xc + rowoff + (unsigned)ox*CHF);
      float u[8];
      unsigned vv[4]={v.x,v.y,v.z,v.w};
      #pragma unroll
      for (int t=0;t<4;t++){
        u[2*t]  = __uint_as_float(vv[t]<<16);
        u[2*t+1]= __uint_as_float(vv[t]&0xffff0000u);
      }
      #pragma unroll
      for (int dx=0;dx<5;dx++){
        int p = j-dx;
        if (p<0 || p>3) continue;
        acc[p][0]=fmaf(u[0],w0[dx].x,acc[p][0]);
        acc[p][1]=fmaf(u[1],w0[dx].y,acc[p][1]);
        acc[p][2]=fmaf(u[2],w0[dx].z,acc[p][2]);
        acc[p][3]=fmaf(u[3],w0[dx].w,acc[p][3]);
        acc[p][4]=fmaf(u[4],w1[dx].x,acc[p][4]);
        acc[p][5]=fmaf(u[5],w1[dx].y,acc[p][5]);
        acc[p][6]=fmaf(u[6],w1[dx].z,acc[p][6]);
        acc[p][7]=fmaf(u[7],w1[dx].w,acc[p][7]);
      }
    }
  }
  float4 b0 = *(const float4*)(dwb + choff);
  float4 b1 = *(const float4*)(dwb + choff + 4);
  float bb[8]={b0.x,b0.y,b0.z,b0.w,b1.x,b1.y,b1.z,b1.w};
  unsigned obase = ((unsigned)(b<<14) + ((unsigned)yq<<7) + (unsigned)x0)*CHF + choff;
  #pragma unroll
  for (int p=0;p<4;p++){
    uint4 cv4 = *(const uint4*)(xc + obase + (unsigned)p*CHF);
    unsigned vv[4]={cv4.x,cv4.y,cv4.z,cv4.w};
    bf16 o[8];
    #pragma unroll
    for (int t=0;t<4;t++){
      float c0 = __uint_as_float(vv[t]<<16);
      float c1 = __uint_as_float(vv[t]&0xffff0000u);
      o[2*t]   = f2b(c0 + geluf(acc[p][2*t]  + bb[2*t]));
      o[2*t+1] = f2b(c1 + geluf(acc[p][2*t+1]+ bb[2*t+1]));
    }
    *(uint4*)(sv + obase + (unsigned)p*CHF) = *(const uint4*)o;
  }
}

// ---------------- host ----------------
extern "C" void kernel_launch(void* const* d_in, const int* in_sizes, int n_in,
                              void* d_out, int out_size, void* d_ws, size_t ws_size,
                              hipStream_t stream){
  const float* x    = (const float*)d_in[0];
  const float* td   = (const float*)d_in[1];
  const int*   rpi  = (const int*)d_in[3];
  const float* n1g  = (const float*)d_in[6];
  const float* n1b  = (const float*)d_in[7];
  const float* n2g  = (const float*)d_in[8];
  const float* n2b  = (const float*)d_in[9];
  const float* wqkv = (const float*)d_in[10];
  const float* wqkvb= (const float*)d_in[11];
  const float* wq   = (const float*)d_in[12];
  const float* wqb  = (const float*)d_in[13];
  const float* wk   = (const float*)d_in[14];
  const float* wkb  = (const float*)d_in[15];
  const float* wv   = (const float*)d_in[16];
  const float* wvb  = (const float*)d_in[17];
  const float* atds = (const float*)d_in[18];
  const float* acaw = (const float*)d_in[19];
  const float* acab = (const float*)d_in[20];
  const float* rpbt = (const float*)d_in[21];
  const float* winw = (const float*)d_in[22];
  const float* winb = (const float*)d_in[23];
  const float* tdw  = (const float*)d_in[24];
  const float* tdbb = (const float*)d_in[25];
  const float* f1w  = (const float*)d_in[26];
  const float* f1b  = (const float*)d_in[27];
  const float* dww  = (const float*)d_in[28];
  const float* dwb  = (const float*)d_in[29];
  const float* f2w  = (const float*)d_in[30];
  const float* f2bb = (const float*)d_in[31];
  float* out = (float*)d_out;

  const size_t QKV_BYTES = (size_t)NT*576*2;   // 75,497,472
  const size_t XN_BYTES  = (size_t)NT*CC*2;    // 25,165,824
  const size_t XC_BYTES  = (size_t)NT*CHF*2;   // 58,720,256

  char* base = (char*)d_ws;
  size_t off = 0;
  auto give = [&](size_t bytes)->char*{
    off = (off + 255) & ~(size_t)255;
    char* r = base + off; off += bytes; return r;
  };
  char*   qkv_r = give(QKV_BYTES);
  char*   xn_r  = give(XN_BYTES);
  char*   sim_r = give(XN_BYTES);
  bf16*   xacc  = (bf16*)  give(XN_BYTES);
  int*    tkid  = (int*)   give((size_t)NT*4);
  int*    sidx  = (int*)   give((size_t)NT*4);
  double* kn    = (double*)give((size_t)NB*64*RDIM*8);
  float*  vbuf  = (float*) give((size_t)NB*64*CC*4);
  float*  tdf   = (float*) give((size_t)NB*64*DTD*4);
  int*    chist = (int*)   give((size_t)NB*64*64*4);
  int*    coff  = (int*)   give((size_t)NB*64*64*4);
  int*    bstart= (int*)   give((size_t)NB*64*4);
  bf16*   rpbq  = (bf16*)  give((size_t)NHEADS*256*256*2);  // 786KB
  bf16*   wqkvt = (bf16*)  give((size_t)192*576*2);
  bf16*   f1wt  = (bf16*)  give((size_t)192*384*2);
  bf16*   f2wt  = (bf16*)  give((size_t)448*192*2);
  bf16*   winwt = (bf16*)  give((size_t)192*192*2);
  bf16*   acawt = (bf16*)  give((size_t)192*192*2);
  double* gw    = (double*)give((size_t)1920*8);
  double* S12   = (double*)give((size_t)20*8);

  if (off > ws_size){
    k_sentinel<<<(out_size+255)/256,256,0,stream>>>(out, out_size, (float)(ws_size>>20));
    return;
  }

  bf16*  qkv  = (bf16*)qkv_r;
  bf16*  xc   = (bf16*)qkv_r;                  // alias: qkv dead after k_acattn
  bf16*  sv   = (bf16*)(qkv_r + XC_BYTES);     // alias: spans qkv-tail + xn + sim
  bf16*  atmp = (bf16*)xn_r;                   // yw/yg scratch (xn no longer materialized)
  float* sim  = (float*)sim_r;

  // weight converts (tiny)
  k_wt<<<(192*576+255)/256,256,0,stream>>>(wqkv, wqkvt, 192, 576);
  k_wt<<<(192*384+255)/256,256,0,stream>>>(f1w, f1wt, 192, 384);
  k_wt<<<(448*192+255)/256,256,0,stream>>>(f2w, f2wt, 448, 192);
  k_wt<<<(192*192+255)/256,256,0,stream>>>(winw, winwt, 192, 192);
  k_wt<<<(192*192+255)/256,256,0,stream>>>(acaw, acawt, 192, 192);
  k_gw<<<1,256,0,stream>>>(n1g, n1b, wq, wqb, gw, S12);
  // Phase A: fused-LN qkv -> window attention (init residual accumulator)
  k_mm<192,192,576,0,0,1><<<dim3(NT/64,9),256,0,stream>>>(nullptr, wqkvt, wqkvb, nullptr, qkv, x, n1g, n1b);
  k_rpbq<<<NHEADS*256*256/256,256,0,stream>>>(rpi, rpbt, rpbq);
  k_winattn<<<NB*64*NHEADS,256,0,stream>>>(qkv, rpbq, atmp);
  k_mm<192,192,192,0,3,0><<<dim3(NT/64,3),256,0,stream>>>(atmp, winwt, winb, x, xacc, nullptr, nullptr, nullptr);
  // Dict projections + sim/argmax (f64 chain) + stable sort
  k_kn<<<4,64,0,stream>>>(td, wk, wkb, kn);
  k_v<<<(NB*64*CC)/256,256,0,stream>>>(td, wv, wvb, vbuf);
  k_tdf<<<(NB*64*DTD)/256,256,0,stream>>>(td, tdw, tdbb, tdf);
  k_sim<<<NT/32,256,0,stream>>>(x, gw, S12, kn, atds, sim, tkid);
  k_hist<<<NB*64,256,0,stream>>>(tkid, chist);
  k_scan<<<NB,64,0,stream>>>(chist, coff, bstart);
  k_place<<<NB*64,256,0,stream>>>(tkid, coff, bstart, sidx);
  // Grouped attention (last qkv reader), then residual adds
  k_acattn<<<NB*128*NHEADS,256,0,stream>>>(qkv, sidx, atmp);
  k_mm<192,192,192,0,4,0><<<dim3(NT/64,3),256,0,stream>>>(atmp, acawt, acab, sidx, xacc, nullptr, nullptr, nullptr);
  k_xatd<<<NT/8,64,0,stream>>>(sim, vbuf, xacc);
  // Phase B: FFN (xc aliases qkv; sv aliases dead regions); fc1 fuses LN2 (bf16 xacc input)
  k_tdgather<<<NT*64/256,256,0,stream>>>(tdf, tkid, xc);
  k_mm<192,192,448,1,0,2><<<dim3(NT/64,6),256,0,stream>>>(nullptr, f1wt, f1b, nullptr, xc, xacc, n2g, n2b);
  k_dw<<<NT*56/4/256,256,0,stream>>>(xc, dww, dwb, sv);
  k_mm<448,64,192,0,2,0><<<dim3(NT/64,3),256,0,stream>>>(sv, f2wt, f2bb, xacc, out, nullptr, nullptr, nullptr);
}

// Round 19
// 537.945 us; speedup vs baseline: 1.1012x; 1.1012x over previous
//
#include <hip/hip_runtime.h>
#include <hip/hip_bf16.h>
#include <math.h>

typedef __hip_bfloat16 bf16;
typedef short bf16x8 __attribute__((ext_vector_type(8)));
typedef float f32x4 __attribute__((ext_vector_type(4)));

#define NB 4
#define HH 128
#define WWID 128
#define CC 192
#define NPB (HH*WWID)      // 16384 tokens per batch
#define NT (NB*NPB)        // 65536 total tokens
#define NHEADS 6
#define HD 32
#define NTOK 64
#define RDIM 10
#define DTD 64
#define MLPH 384
#define CHF (MLPH+DTD)     // 448

__device__ __forceinline__ float b2f(bf16 v){ return __bfloat162float(v); }
__device__ __forceinline__ bf16  f2b(float v){ return __float2bfloat16(v); }
__device__ __forceinline__ float bfu(unsigned short u){ return __uint_as_float(((unsigned)u)<<16); }
__device__ __forceinline__ float geluf(float v){ return 0.5f*v*(1.0f+erff(v*0.70710678118654752f)); }
__device__ __forceinline__ int rg3(int v){ return v<112?0:(v<120?1:2); }

__device__ __forceinline__ void gload16(const void* g, void* l){
  __builtin_amdgcn_global_load_lds((const __attribute__((address_space(1))) unsigned*)g,
                                   (__attribute__((address_space(3))) unsigned*)l, 16, 0, 0);
}

__device__ __forceinline__ float wsumf(float v){
  #pragma unroll
  for (int m=32;m>0;m>>=1) v += __shfl_xor(v,m);
  return v;
}

__global__ void k_sentinel(float* out, int n, float v){
  int i = blockIdx.x*256+threadIdx.x;
  if (i<n) out[i]=v;
}

// ---------------- LayerNorm ----------------
template<int BF16IN>
__global__ __launch_bounds__(256) void k_ln(const float* __restrict__ xf, const bf16* __restrict__ xb,
                                            const float* __restrict__ g, const float* __restrict__ be,
                                            bf16* __restrict__ out){
  int wave = threadIdx.x>>6, lane = threadIdx.x&63;
  int tok = blockIdx.x*4 + wave;
  size_t base = (size_t)tok*CC;
  float v0,v1,v2;
  if (BF16IN){ v0=b2f(xb[base+lane]); v1=b2f(xb[base+lane+64]); v2=b2f(xb[base+lane+128]); }
  else { v0=xf[base+lane]; v1=xf[base+lane+64]; v2=xf[base+lane+128]; }
  float s = wsumf(v0+v1+v2);
  float mu = s*(1.0f/192.0f);
  float d0=v0-mu, d1=v1-mu, d2=v2-mu;
  float q = wsumf(d0*d0+d1*d1+d2*d2);
  float rs = rsqrtf(q*(1.0f/192.0f)+1e-5f);
  out[base+lane]     = f2b(d0*rs*g[lane]     + be[lane]);
  out[base+lane+64]  = f2b(d1*rs*g[lane+64]  + be[lane+64]);
  out[base+lane+128] = f2b(d2*rs*g[lane+128] + be[lane+128]);
}

// ---------------- weight converters ----------------
__global__ __launch_bounds__(256) void k_wt(const float* __restrict__ W, bf16* __restrict__ Wt, int K, int N){
  int i = blockIdx.x*256+threadIdx.x;
  if (i < K*N){ int n = i / K, k = i - n*K; Wt[i] = f2b(W[(size_t)k*N + n]); }
}

// gw[c][r] = n1g[c]*wq[c][r];  S12[r]=S1_r, S12[10+r]=S2_r+wqb[r]  (f64, for k_sim)
__global__ __launch_bounds__(256) void k_gw(const float* __restrict__ n1g, const float* __restrict__ n1b,
                                            const float* __restrict__ wq, const float* __restrict__ wqb,
                                            double* __restrict__ gw, double* __restrict__ S12){
  int ti=threadIdx.x;
  for (int i=ti;i<1920;i+=256){
    int c=i/10;
    gw[i]=(double)n1g[c]*(double)wq[i];
  }
  if (ti<10){
    double s1=0.0,s2=0.0;
    for (int c=0;c<192;c++){
      double w=(double)wq[c*10+ti];
      s1=fma((double)n1g[c],w,s1);
      s2=fma((double)n1b[c],w,s2);
    }
    S12[ti]=s1; S12[10+ti]=s2+(double)wqb[ti];
  }
}

// ---------------- tiny dict projections ----------------
__global__ __launch_bounds__(64) void k_kn(const float* __restrict__ td, const float* __restrict__ wk,
                                           const float* __restrict__ wkb, double* __restrict__ kn){
  int t = blockIdx.x*64+threadIdx.x;            // 0..255 = (b,m)
  double kk[10]; double sq=0.0;
  const float* tr = td + (size_t)t*CC;
  #pragma unroll
  for (int r=0;r<10;r++) kk[r]=(double)wkb[r];
  for (int k=0;k<CC;k++){
    double tv=(double)tr[k];
    #pragma unroll
    for (int r=0;r<10;r++) kk[r] += tv*(double)wk[k*10+r];
  }
  #pragma unroll
  for (int r=0;r<10;r++) sq += kk[r]*kk[r];
  double inv = 1.0/fmax(sqrt(sq),1e-12);
  #pragma unroll
  for (int r=0;r<10;r++) kn[t*10+r]=kk[r]*inv;
}

__global__ __launch_bounds__(256) void k_v(const float* __restrict__ td, const float* __restrict__ wv,
                                           const float* __restrict__ wvb, float* __restrict__ vb){
  int idx = blockIdx.x*256+threadIdx.x;         // < 4*64*192
  int c = idx % CC; int bm = idx / CC;
  const float* tr = td + (size_t)bm*CC;
  float a = wvb[c];
  for (int k=0;k<CC;k++) a = fmaf(tr[k], wv[(size_t)k*CC+c], a);
  vb[idx] = a;
}

__global__ __launch_bounds__(256) void k_tdf(const float* __restrict__ td, const float* __restrict__ w,
                                             const float* __restrict__ bb, float* __restrict__ tdf){
  int idx = blockIdx.x*256+threadIdx.x;         // < 4*64*64
  int d = idx & 63; int bm = idx >> 6;
  const float* tr = td + (size_t)bm*CC;
  float a = bb[d];
  for (int k=0;k<CC;k++) a = fmaf(tr[k], w[(size_t)k*64+d], a);
  tdf[idx] = a;
}

// rpbq[h][q][k] = rpbt[rpi[q*256+k]*6+h]
__global__ __launch_bounds__(256) void k_rpbq(const int* __restrict__ rpi, const float* __restrict__ rpbt,
                                              bf16* __restrict__ rpbq){
  int idx = blockIdx.x*256+threadIdx.x;         // < 6*65536
  int h = idx>>16; int qk = idx&65535;
  rpbq[idx] = f2b(rpbt[rpi[qk]*6 + h]);
}

// ---------------- sim / argmax v5: 32 tok/block, thread=(tok,subslice), 12 f64 chains ----------------
__global__ __launch_bounds__(256) void k_sim(const float* __restrict__ x, const double* __restrict__ gw,
                                             const double* __restrict__ S12, const double* __restrict__ kn,
                                             const float* __restrict__ atds,
                                             float* __restrict__ sim, int* __restrict__ tkid){
  __shared__ double gws[1920];                   // 15.4KB
  __shared__ double S12s[20];
  __shared__ double ql[32][10];                  // 2.5KB
  int ti = threadIdx.x;
  int blk = blockIdx.x;                          // NT/32 = 2048 blocks
  for (int i=ti;i<1920;i+=256) gws[i]=gw[i];
  if (ti<20) S12s[ti]=S12[ti];
  __syncthreads();
  {
    int tok = ti>>3, sub = ti&7;
    const float* xr = x + ((size_t)(blk*32+tok))*192 + sub*24;
    float xv[24];
    #pragma unroll
    for (int q4=0;q4<6;q4++) *(float4*)(xv+q4*4) = *(const float4*)(xr+q4*4);
    double acc[10]; double s=0.0, s2=0.0;
    #pragma unroll
    for (int r=0;r<10;r++) acc[r]=0.0;
    #pragma unroll
    for (int c=0;c<24;c++){
      double v=(double)xv[c];
      s+=v; s2=fma(v,v,s2);
      const double* gr = gws + (sub*24+c)*10;
      #pragma unroll
      for (int r=0;r<10;r++) acc[r]=fma(v,gr[r],acc[r]);
    }
    #pragma unroll
    for (int m=1;m<8;m<<=1){
      s+=__shfl_xor(s,m); s2+=__shfl_xor(s2,m);
      #pragma unroll
      for (int r=0;r<10;r++) acc[r]+=__shfl_xor(acc[r],m);
    }
    if (sub==0){
      double mu=s*(1.0/192.0);
      double var=s2*(1.0/192.0)-mu*mu;
      double rs=1.0/sqrt(var+1e-5);
      #pragma unroll
      for (int r=0;r<10;r++) ql[tok][r]=rs*(acc[r]-mu*S12s[r])+S12s[10+r];
    }
  }
  __syncthreads();
  int wave = ti>>6, lane = ti&63;
  int b = blk>>9;                                // 512 blocks per batch
  double kr[10];
  #pragma unroll
  for (int r2=0;r2<10;r2++) kr[r2]=kn[((size_t)(b*64+lane))*10+r2];
  double asd=fmin(fmax((double)atds[0],0.0),3.0);
  double scl=1.0+asd*4.1588830833596715;         // 1 + clip*ln(64)
  for (int tk=wave; tk<32; tk+=4){
    double dot=0.0, sq=0.0;
    #pragma unroll
    for (int r2=0;r2<10;r2++){
      double qv=ql[tk][r2];
      dot=fma(qv,kr[r2],dot);
      sq =fma(qv,qv,sq);
    }
    dot *= 1.0/fmax(sqrt(sq),1e-12);
    double bv=dot; int bi=lane;
    #pragma unroll
    for (int m2=32;m2>0;m2>>=1){
      double ov=__shfl_xor(bv,m2); int oi=__shfl_xor(bi,m2);
      if (ov>bv || (ov==bv && oi<bi)){ bv=ov; bi=oi; }
    }
    int tokg = blk*32+tk;
    if (lane==0) tkid[tokg]=bi;
    float t=(float)(dot*scl);
    float pp=__expf(t);
    float ssf=pp;
    #pragma unroll
    for (int m2=32;m2>0;m2>>=1) ssf+=__shfl_xor(ssf,m2);
    sim[(size_t)tokg*64+lane]=pp/ssf;
  }
}

// ---------------- MFMA GEMM: C[M][N] = A[M][K] @ Wt^T, tile 64x64, 4 waves ----------------
// Staging: async global_load_lds (linear LDS dest, pre-swizzled global src) when KC/8 % 8 == 0,
//          else register path with XOR on LDS dest. Read side always XORs: LDS[r][u^(r&7)]=G[r][u].
// OUTMODE 0: bf16 out (+ACT gelu). 2: f32 out = bf16(aux)[o] + v.
// 3: xacc-init = f32 x(aux)[perm] + v (window-reverse perm).  4: xacc += v (sidx perm, RMW).
template<int K, int KC, int NS, int ACT, int OUTMODE>
__global__ __launch_bounds__(256) void k_mm(const bf16* __restrict__ A, const bf16* __restrict__ Wt,
                                            const float* __restrict__ bias, const void* __restrict__ aux,
                                            void* __restrict__ outp){
  __shared__ __align__(16) char As[64*KC*2];
  __shared__ __align__(16) char Ws[64*KC*2];
  int row0 = blockIdx.x*64, n0 = blockIdx.y*64;
  int ti = threadIdx.x;
  int wave = ti>>6, lane = ti&63, g = lane>>4, l15 = lane&15;
  f32x4 acc[4];
  #pragma unroll
  for (int mt=0;mt<4;mt++){ f32x4 z={0.f,0.f,0.f,0.f}; acc[mt]=z; }
  const int KC8 = KC/8;
  for (int c0=0; c0<K; c0+=KC){
    if (c0) __syncthreads();
    if constexpr ((KC/8)%8==0){
      // async direct-to-LDS: dest linear (wave-uniform base + lane*16), src unit pre-swizzled
      for (int u0 = wave*64; u0 < 64*KC8; u0 += 256){
        int u = u0 + lane;
        int r = u/KC8, kc = u - r*KC8;
        int kcs = kc ^ (r&7);                    // stays in [0,KC8) since KC8 % 8 == 0
        gload16(A  + (size_t)(row0+r)*K + c0 + (kcs<<3), As + (size_t)u0*16);
        gload16(Wt + (size_t)(n0+r)*K  + c0 + (kcs<<3), Ws + (size_t)u0*16);
      }
    } else {
      for (int u=ti; u<64*KC8; u+=256){
        int r = u/KC8, kc = u-r*KC8;
        uint4 va = *(const uint4*)(A  + (size_t)(row0+r)*K + c0 + kc*8);
        *(uint4*)(As + ((r*(KC*2) + kc*16) ^ ((r&7)<<4))) = va;
        uint4 vw = *(const uint4*)(Wt + (size_t)(n0+r)*K + c0 + kc*8);
        *(uint4*)(Ws + ((r*(KC*2) + kc*16) ^ ((r&7)<<4))) = vw;
      }
    }
    __syncthreads();
    #pragma unroll
    for (int ks=0; ks<KC/32; ks++){
      int rw = wave*16 + l15;
      bf16x8 bfr = *(const bf16x8*)(Ws + ((rw*(KC*2) + ks*64 + g*16) ^ ((rw&7)<<4)));
      #pragma unroll
      for (int mt=0;mt<4;mt++){
        int ra = mt*16 + l15;
        bf16x8 af = *(const bf16x8*)(As + ((ra*(KC*2) + ks*64 + g*16) ^ ((ra&7)<<4)));
        acc[mt] = __builtin_amdgcn_mfma_f32_16x16x32_bf16(af, bfr, acc[mt], 0,0,0);
      }
    }
  }
  int col = n0 + wave*16 + l15;
  float bb = bias[col];
  #pragma unroll
  for (int mt=0;mt<4;mt++){
    #pragma unroll
    for (int j=0;j<4;j++){
      int row = row0 + mt*16 + g*4 + j;
      float v = acc[mt][j] + bb;
      if (OUTMODE==0){
        ((bf16*)outp)[(size_t)row*NS + col] = f2b(ACT ? geluf(v) : v);
      } else if (OUTMODE==2){
        size_t o = (size_t)row*NS + col;
        ((float*)outp)[o] = b2f(((const bf16*)aux)[o]) + v;
      } else if (OUTMODE==3){
        int win=row>>8, tii=row&255;
        int b=win>>6, wloc=win&63;
        int wy=wloc>>3, wx=wloc&7, tyy=tii>>4, txx=tii&15;
        int oy=(wy*16+tyy+8)&127, ox=(wx*16+txx+8)&127;
        size_t o=((size_t)(b*NPB + oy*128 + ox))*NS + col;
        ((bf16*)outp)[o] = f2b(((const float*)aux)[o] + v);
      } else {
        int orow=(row & ~(NPB-1)) + ((const int*)aux)[row];
        size_t o=(size_t)orow*NS + col;
        bf16* xo=(bf16*)outp;
        xo[o] = f2b(b2f(xo[o]) + v);
      }
    }
  }
}

// ---------------- scalar GEMM core (kept for xatd) ----------------
__device__ __forceinline__ float ldw(const bf16* p, size_t i){ return __bfloat162float(p[i]); }
__device__ __forceinline__ float ldw(const float* p, size_t i){ return p[i]; }

template<int KD, int CB, typename WT>
__device__ __forceinline__ void gemm_core(const float (*As)[KD], const WT* __restrict__ W, int N, float (&acc)[8][CB]){
  int tid = threadIdx.x;
  for (int k=0;k<KD;k+=4){
    float w0[CB],w1[CB],w2[CB],w3[CB];
    #pragma unroll
    for (int j=0;j<CB;j++){
      int c = tid + 64*j;
      w0[j]=ldw(W,(size_t)(k+0)*N+c);
      w1[j]=ldw(W,(size_t)(k+1)*N+c);
      w2[j]=ldw(W,(size_t)(k+2)*N+c);
      w3[j]=ldw(W,(size_t)(k+3)*N+c);
    }
    #pragma unroll
    for (int r=0;r<8;r++){
      float4 a = *reinterpret_cast<const float4*>(&As[r][k]);
      #pragma unroll
      for (int j=0;j<CB;j++)
        acc[r][j]=fmaf(a.x,w0[j],fmaf(a.y,w1[j],fmaf(a.z,w2[j],fmaf(a.w,w3[j],acc[r][j]))));
    }
  }
}

// xacc += sim @ v
__global__ __launch_bounds__(64) void k_xatd(const float* __restrict__ sim, const float* __restrict__ vb,
                                             bf16* __restrict__ xacc){
  __shared__ __align__(16) float As[8][64];
  int row0=blockIdx.x*8;
  for (int idx=threadIdx.x; idx<8*64; idx+=64){
    int r=idx>>6, k=idx&63;
    As[r][k]=sim[(size_t)(row0+r)*64+k];
  }
  __syncthreads();
  float acc[8][3]={};
  const float* Wv = vb + (size_t)(row0>>14)*64*CC;
  gemm_core<64,3>(As, Wv, CC, acc);
  int tid=threadIdx.x;
  #pragma unroll
  for (int j=0;j<3;j++){
    int c=tid+64*j;
    #pragma unroll
    for (int r=0;r<8;r++){
      size_t o=(size_t)(row0+r)*CC+c;
      xacc[o]=f2b(b2f(xacc[o])+acc[r][j]);
    }
  }
}

__global__ __launch_bounds__(256) void k_tdgather(const float* __restrict__ tdf, const int* __restrict__ tkid,
                                                  bf16* __restrict__ xc){
  int idx = blockIdx.x*256+threadIdx.x;   // NT*64
  int d = idx & 63; int tok = idx >> 6;
  int b = tok >> 14;
  int m = tkid[tok];
  xc[(size_t)tok*CHF + MLPH + d] = f2b(tdf[((size_t)((b<<6)+m))*64 + d]);
}

// ---------------- stable counting sort of tk_id ----------------
__global__ __launch_bounds__(256) void k_hist(const int* __restrict__ tkid, int* __restrict__ chist){
  __shared__ int h[64];
  int b = blockIdx.x>>6, ch = blockIdx.x&63;
  if (threadIdx.x<64) h[threadIdx.x]=0;
  __syncthreads();
  int v = tkid[b*NPB + ch*256 + threadIdx.x];
  atomicAdd(&h[v],1);
  __syncthreads();
  if (threadIdx.x<64) chist[(size_t)blockIdx.x*64 + threadIdx.x] = h[threadIdx.x];
}

__global__ __launch_bounds__(64) void k_scan(const int* __restrict__ chist, int* __restrict__ coff,
                                             int* __restrict__ bstart){
  int b = blockIdx.x; int v = threadIdx.x;
  __shared__ int tot[64], bs[64];
  int s=0;
  for (int ch=0; ch<64; ch++){
    coff[((size_t)(b*64+ch))*64+v] = s;
    s += chist[((size_t)(b*64+ch))*64+v];
  }
  tot[v]=s;
  __syncthreads();
  if (v==0){ int run=0; for (int u=0;u<64;u++){ bs[u]=run; run+=tot[u]; } }
  __syncthreads();
  bstart[b*64+v] = bs[v];
}

__global__ __launch_bounds__(256) void k_place(const int* __restrict__ tkid, const int* __restrict__ coff,
                                               const int* __restrict__ bstart, int* __restrict__ sidx){
  __shared__ int vals[256];
  int b = blockIdx.x>>6, ch = blockIdx.x&63;
  int tid = threadIdx.x;
  int tok = ch*256 + tid;
  int v = tkid[b*NPB + tok];
  vals[tid]=v;
  __syncthreads();
  int lr=0;
  for (int j=0;j<tid;j++) lr += (vals[j]==v);
  int pos = bstart[b*64+v] + coff[((size_t)(b*64+ch))*64+v] + lr;
  sidx[b*NPB + pos] = tok;
}

// ---------------- AC_MSA grouped attention (MFMA flash, fixed-max softmax) ----------------
__global__ __launch_bounds__(256,4) void k_acattn(const bf16* __restrict__ qkv, const int* __restrict__ sidx,
                                                  bf16* __restrict__ yg){
  __shared__ bf16 Kl[128*32];
  __shared__ bf16 Vt[32*128];
  __shared__ bf16 Ps[4][16*32];
  int bid=blockIdx.x;
  int h = bid % NHEADS; int gg = (bid/NHEADS) & 127; int b = bid/(NHEADS*128);
  int ti = threadIdx.x;
  if (ti < 128){
    int srow = b*NPB + sidx[b*NPB + gg*128 + ti];
    const bf16* src = qkv + (size_t)srow*576 + 192 + h*32;
    const uint4* s4 = (const uint4*)src;
    char* kb = (char*)Kl;
    #pragma unroll
    for (int w=0;w<4;w++) *(uint4*)(kb + ((ti*64 + w*16) ^ ((ti&7)<<4))) = s4[w];
    const bf16* vsrc = src + 192;
    char* vbp = (char*)Vt;
    #pragma unroll
    for (int d=0;d<32;d++) *(bf16*)(vbp + ((d*256 + ti*2) ^ ((d&7)<<4))) = vsrc[d];
  }
  __syncthreads();
  int wave=ti>>6, lane=ti&63, g=lane>>4, l15=lane&15;
  bf16x8 qf[2];
  #pragma unroll
  for (int qt=0;qt<2;qt++){
    int q = wave*32 + qt*16 + l15;
    int srow = b*NPB + sidx[b*NPB + gg*128 + q];
    qf[qt] = *(const bf16x8*)(qkv + (size_t)srow*576 + h*32 + g*8);
  }
  f32x4 O[2][2]; float lsp[2][4];
  #pragma unroll
  for (int qt=0;qt<2;qt++){
    #pragma unroll
    for (int dt=0;dt<2;dt++){ f32x4 z={0.f,0.f,0.f,0.f}; O[qt][dt]=z; }
    #pragma unroll
    for (int j=0;j<4;j++) lsp[qt][j]=0.f;
  }
  const float rsc=0.17677669529663687f;
  const char* kb=(const char*)Kl; const char* vbp=(const char*)Vt;
  for (int st=0; st<4; st++){
    int r0=st*32+l15, r1=st*32+16+l15;
    bf16x8 kf0 = *(const bf16x8*)(kb + ((r0*64 + g*16) ^ ((r0&7)<<4)));
    bf16x8 kf1 = *(const bf16x8*)(kb + ((r1*64 + g*16) ^ ((r1&7)<<4)));
    int d0=l15, d1=16+l15;
    bf16x8 vf0 = *(const bf16x8*)(vbp + ((d0*256 + st*64 + g*16) ^ ((d0&7)<<4)));
    bf16x8 vf1 = *(const bf16x8*)(vbp + ((d1*256 + st*64 + g*16) ^ ((d1&7)<<4)));
    #pragma unroll
    for (int qt=0;qt<2;qt++){
      f32x4 z={0.f,0.f,0.f,0.f};
      f32x4 s0 = __builtin_amdgcn_mfma_f32_16x16x32_bf16(qf[qt], kf0, z, 0,0,0);
      f32x4 s1 = __builtin_amdgcn_mfma_f32_16x16x32_bf16(qf[qt], kf1, z, 0,0,0);
      float p0[4],p1[4];
      char* pb=(char*)Ps[wave];
      #pragma unroll
      for (int j=0;j<4;j++){
        p0[j]=__expf(fminf(s0[j]*rsc,80.f));
        p1[j]=__expf(fminf(s1[j]*rsc,80.f));
        lsp[qt][j]+=p0[j]+p1[j];
        int q=g*4+j;
        *(bf16*)(pb + ((q*64 + l15*2) ^ ((q&7)<<4)))      = f2b(p0[j]);
        *(bf16*)(pb + ((q*64 + 32 + l15*2) ^ ((q&7)<<4))) = f2b(p1[j]);
      }
      bf16x8 pa = *(const bf16x8*)((const char*)Ps[wave] + ((l15*64 + g*16) ^ ((l15&7)<<4)));
      O[qt][0]=__builtin_amdgcn_mfma_f32_16x16x32_bf16(pa, vf0, O[qt][0], 0,0,0);
      O[qt][1]=__builtin_amdgcn_mfma_f32_16x16x32_bf16(pa, vf1, O[qt][1], 0,0,0);
    }
  }
  #pragma unroll
  for (int qt=0;qt<2;qt++){
    #pragma unroll
    for (int msk=1; msk<16; msk<<=1){
      #pragma unroll
      for (int j=0;j<4;j++) lsp[qt][j]+=__shfl_xor(lsp[qt][j],msk);
    }
    #pragma unroll
    for (int j=0;j<4;j++){
      float inv=1.0f/lsp[qt][j];
      int q = wave*32 + qt*16 + g*4 + j;
      bf16* yo = yg + ((size_t)(b*NPB + gg*128 + q))*CC + h*32;
      yo[l15]    = f2b(O[qt][0][j]*inv);
      yo[16+l15] = f2b(O[qt][1][j]*inv);
    }
  }
}

// ---------------- shifted-window attention (MFMA flash, fixed-max softmax) ----------------
__global__ __launch_bounds__(256,3) void k_winattn(const bf16* __restrict__ qkv, const bf16* __restrict__ rpbq,
                                                   bf16* __restrict__ yw){
  __shared__ bf16 Kl[256*32];
  __shared__ bf16 Vt[32*256];
  __shared__ bf16 Ps[4][16*32];
  int bid = blockIdx.x;
  int h = bid % NHEADS; int win = bid / NHEADS;
  int b = win >> 6; int wloc = win & 63;
  int wy = wloc >> 3, wx = wloc & 7;
  int ti = threadIdx.x;
  {
    int ty=ti>>4, tx=ti&15;
    int oy=(wy*16+ty+8)&127, ox=(wx*16+tx+8)&127;
    const bf16* src = qkv + (size_t)(b*NPB+oy*128+ox)*576 + 192 + h*32;
    const uint4* s4 = (const uint4*)src;
    char* kb = (char*)Kl;
    #pragma unroll
    for (int w=0;w<4;w++) *(uint4*)(kb + ((ti*64 + w*16) ^ ((ti&7)<<4))) = s4[w];
    const bf16* vsrc = src + 192;
    char* vbp = (char*)Vt;
    #pragma unroll
    for (int d=0;d<32;d++) *(bf16*)(vbp + ((d*512 + ti*2) ^ ((d&7)<<4))) = vsrc[d];
  }
  __syncthreads();
  int wave=ti>>6, lane=ti&63, g=lane>>4, l15=lane&15;
  bf16x8 qf[4];
  #pragma unroll
  for (int qt=0;qt<4;qt++){
    int ty=wave*4+qt, tx=l15;
    int oy=(wy*16+ty+8)&127, ox=(wx*16+tx+8)&127;
    qf[qt] = *(const bf16x8*)(qkv + (size_t)(b*NPB+oy*128+ox)*576 + h*32 + g*8);
  }
  f32x4 O[4][2]; float lsp[4][4];
  #pragma unroll
  for (int qt=0;qt<4;qt++){
    #pragma unroll
    for (int dt=0;dt<2;dt++){ f32x4 z={0.f,0.f,0.f,0.f}; O[qt][dt]=z; }
    #pragma unroll
    for (int j=0;j<4;j++) lsp[qt][j]=0.f;
  }
  const float rsc=0.17677669529663687f;
  int rxk = rg3(wx*16+l15);
  int rxq[4], ryq[4];
  #pragma unroll
  for (int j=0;j<4;j++) rxq[j]=rg3(wx*16+g*4+j);
  #pragma unroll
  for (int qt=0;qt<4;qt++) ryq[qt]=rg3(wy*16+wave*4+qt);
  const char* kb=(const char*)Kl; const char* vbp=(const char*)Vt;
  for (int st=0; st<8; st++){
    int r0=st*32+l15, r1=st*32+16+l15;
    bf16x8 kf0 = *(const bf16x8*)(kb + ((r0*64 + g*16) ^ ((r0&7)<<4)));
    bf16x8 kf1 = *(const bf16x8*)(kb + ((r1*64 + g*16) ^ ((r1&7)<<4)));
    int d0=l15, d1=16+l15;
    bf16x8 vf0 = *(const bf16x8*)(vbp + ((d0*512 + st*64 + g*16) ^ ((d0&7)<<4)));
    bf16x8 vf1 = *(const bf16x8*)(vbp + ((d1*512 + st*64 + g*16) ^ ((d1&7)<<4)));
    int rk0 = rg3(wy*16+st*2)*3   + rxk;
    int rk1 = rg3(wy*16+st*2+1)*3 + rxk;
    #pragma unroll
    for (int qt=0;qt<4;qt++){
      f32x4 z={0.f,0.f,0.f,0.f};
      f32x4 s0 = __builtin_amdgcn_mfma_f32_16x16x32_bf16(qf[qt], kf0, z, 0,0,0);
      f32x4 s1 = __builtin_amdgcn_mfma_f32_16x16x32_bf16(qf[qt], kf1, z, 0,0,0);
      int qr0 = wave*64 + qt*16 + g*4;
      float p0[4],p1[4];
      char* pb=(char*)Ps[wave];
      #pragma unroll
      for (int j=0;j<4;j++){
        const bf16* rb = rpbq + (((size_t)h*256 + qr0 + j)<<8) + st*32;
        int rq = ryq[qt]*3 + rxq[j];
        float b0 = b2f(rb[l15])    + (rq!=rk0 ? -100.f : 0.f);
        float b1 = b2f(rb[16+l15]) + (rq!=rk1 ? -100.f : 0.f);
        p0[j]=__expf(fminf(fmaf(s0[j],rsc,b0),80.f));
        p1[j]=__expf(fminf(fmaf(s1[j],rsc,b1),80.f));
        lsp[qt][j]+=p0[j]+p1[j];
        int q=g*4+j;
        *(bf16*)(pb + ((q*64 + l15*2) ^ ((q&7)<<4)))      = f2b(p0[j]);
        *(bf16*)(pb + ((q*64 + 32 + l15*2) ^ ((q&7)<<4))) = f2b(p1[j]);
      }
      bf16x8 pa = *(const bf16x8*)((const char*)Ps[wave] + ((l15*64 + g*16) ^ ((l15&7)<<4)));
      O[qt][0]=__builtin_amdgcn_mfma_f32_16x16x32_bf16(pa, vf0, O[qt][0], 0,0,0);
      O[qt][1]=__builtin_amdgcn_mfma_f32_16x16x32_bf16(pa, vf1, O[qt][1], 0,0,0);
    }
  }
  #pragma unroll
  for (int qt=0;qt<4;qt++){
    #pragma unroll
    for (int msk=1; msk<16; msk<<=1){
      #pragma unroll
      for (int j=0;j<4;j++) lsp[qt][j]+=__shfl_xor(lsp[qt][j],msk);
    }
    #pragma unroll
    for (int j=0;j<4;j++){
      float inv=1.0f/lsp[qt][j];
      int q = wave*64 + qt*16 + g*4 + j;
      bf16* yo = yw + ((size_t)win*256 + q)*CC + h*32;
      yo[l15]    = f2b(O[qt][0][j]*inv);
      yo[16+l15] = f2b(O[qt][1][j]*inv);
    }
  }
}

// ---------------- depthwise conv v3 (256,4 known-good): 4 px/thread, f32 weights, 32-bit addr ----------------
__global__ __launch_bounds__(256,4) void k_dw(const bf16* __restrict__ xc, const float* __restrict__ dww,
                                              const float* __restrict__ dwb, bf16* __restrict__ sv){
  int tid = blockIdx.x*256 + threadIdx.x;       // < 16384*56 = 917504
  int ch8 = tid % 56; int pt = tid / 56;
  int x0 = (pt & 31)*4; int yq = (pt>>5)&127; int b = pt>>12;
  float acc[4][8];
  #pragma unroll
  for (int p=0;p<4;p++)
    #pragma unroll
    for (int c=0;c<8;c++) acc[p][c]=0.f;
  unsigned choff = (unsigned)ch8*8;
  const float* wp = dww + choff;
  #pragma unroll
  for (int dy=0;dy<5;dy++){
    int yy = yq+dy-2;
    if ((unsigned)yy>127u) continue;
    float4 w0[5], w1[5];
    #pragma unroll
    for (int dx=0;dx<5;dx++){
      w0[dx] = *(const float4*)(wp + (dy*5+dx)*CHF);
      w1[dx] = *(const float4*)(wp + (dy*5+dx)*CHF + 4);
    }
    unsigned rowoff = ((unsigned)(b<<14) + ((unsigned)yy<<7))*CHF + choff;
    #pragma unroll
    for (int j=0;j<8;j++){
      int ox = x0-2+j;
      if ((unsigned)ox>127u) continue;
      uint4 v = *(const uint4*)(xc + rowoff + (unsigned)ox*CHF);
      float u[8];
      unsigned vv[4]={v.x,v.y,v.z,v.w};
      #pragma unroll
      for (int t=0;t<4;t++){
        u[2*t]  = __uint_as_float(vv[t]<<16);
        u[2*t+1]= __uint_as_float(vv[t]&0xffff0000u);
      }
      #pragma unroll
      for (int dx=0;dx<5;dx++){
        int p = j-dx;
        if (p<0 || p>3) continue;
        acc[p][0]=fmaf(u[0],w0[dx].x,acc[p][0]);
        acc[p][1]=fmaf(u[1],w0[dx].y,acc[p][1]);
        acc[p][2]=fmaf(u[2],w0[dx].z,acc[p][2]);
        acc[p][3]=fmaf(u[3],w0[dx].w,acc[p][3]);
        acc[p][4]=fmaf(u[4],w1[dx].x,acc[p][4]);
        acc[p][5]=fmaf(u[5],w1[dx].y,acc[p][5]);
        acc[p][6]=fmaf(u[6],w1[dx].z,acc[p][6]);
        acc[p][7]=fmaf(u[7],w1[dx].w,acc[p][7]);
      }
    }
  }
  float4 b0 = *(const float4*)(dwb + choff);
  float4 b1 = *(const float4*)(dwb + choff + 4);
  float bb[8]={b0.x,b0.y,b0.z,b0.w,b1.x,b1.y,b1.z,b1.w};
  unsigned obase = ((unsigned)(b<<14) + ((unsigned)yq<<7) + (unsigned)x0)*CHF + choff;
  #pragma unroll
  for (int p=0;p<4;p++){
    uint4 cv4 = *(const uint4*)(xc + obase + (unsigned)p*CHF);
    unsigned vv[4]={cv4.x,cv4.y,cv4.z,cv4.w};
    bf16 o[8];
    #pragma unroll
    for (int t=0;t<4;t++){
      float c0 = __uint_as_float(vv[t]<<16);
      float c1 = __uint_as_float(vv[t]&0xffff0000u);
      o[2*t]   = f2b(c0 + geluf(acc[p][2*t]  + bb[2*t]));
      o[2*t+1] = f2b(c1 + geluf(acc[p][2*t+1]+ bb[2*t+1]));
    }
    *(uint4*)(sv + obase + (unsigned)p*CHF) = *(const uint4*)o;
  }
}

// ---------------- host ----------------
extern "C" void kernel_launch(void* const* d_in, const int* in_sizes, int n_in,
                              void* d_out, int out_size, void* d_ws, size_t ws_size,
                              hipStream_t stream){
  const float* x    = (const float*)d_in[0];
  const float* td   = (const float*)d_in[1];
  const int*   rpi  = (const int*)d_in[3];
  const float* n1g  = (const float*)d_in[6];
  const float* n1b  = (const float*)d_in[7];
  const float* n2g  = (const float*)d_in[8];
  const float* n2b  = (const float*)d_in[9];
  const float* wqkv = (const float*)d_in[10];
  const float* wqkvb= (const float*)d_in[11];
  const float* wq   = (const float*)d_in[12];
  const float* wqb  = (const float*)d_in[13];
  const float* wk   = (const float*)d_in[14];
  const float* wkb  = (const float*)d_in[15];
  const float* wv   = (const float*)d_in[16];
  const float* wvb  = (const float*)d_in[17];
  const float* atds = (const float*)d_in[18];
  const float* acaw = (const float*)d_in[19];
  const float* acab = (const float*)d_in[20];
  const float* rpbt = (const float*)d_in[21];
  const float* winw = (const float*)d_in[22];
  const float* winb = (const float*)d_in[23];
  const float* tdw  = (const float*)d_in[24];
  const float* tdbb = (const float*)d_in[25];
  const float* f1w  = (const float*)d_in[26];
  const float* f1b  = (const float*)d_in[27];
  const float* dww  = (const float*)d_in[28];
  const float* dwb  = (const float*)d_in[29];
  const float* f2w  = (const float*)d_in[30];
  const float* f2bb = (const float*)d_in[31];
  float* out = (float*)d_out;

  const size_t QKV_BYTES = (size_t)NT*576*2;   // 75,497,472
  const size_t XN_BYTES  = (size_t)NT*CC*2;    // 25,165,824
  const size_t XC_BYTES  = (size_t)NT*CHF*2;   // 58,720,256

  char* base = (char*)d_ws;
  size_t off = 0;
  auto give = [&](size_t bytes)->char*{
    off = (off + 255) & ~(size_t)255;
    char* r = base + off; off += bytes; return r;
  };
  char*   qkv_r = give(QKV_BYTES);
  char*   xn_r  = give(XN_BYTES);
  char*   sim_r = give(XN_BYTES);
  bf16*   xacc  = (bf16*)  give(XN_BYTES);
  int*    tkid  = (int*)   give((size_t)NT*4);
  int*    sidx  = (int*)   give((size_t)NT*4);
  double* kn    = (double*)give((size_t)NB*64*RDIM*8);
  float*  vbuf  = (float*) give((size_t)NB*64*CC*4);
  float*  tdf   = (float*) give((size_t)NB*64*DTD*4);
  int*    chist = (int*)   give((size_t)NB*64*64*4);
  int*    coff  = (int*)   give((size_t)NB*64*64*4);
  int*    bstart= (int*)   give((size_t)NB*64*4);
  bf16*   rpbq  = (bf16*)  give((size_t)NHEADS*256*256*2);  // 786KB
  bf16*   wqkvt = (bf16*)  give((size_t)192*576*2);
  bf16*   f1wt  = (bf16*)  give((size_t)192*384*2);
  bf16*   f2wt  = (bf16*)  give((size_t)448*192*2);
  bf16*   winwt = (bf16*)  give((size_t)192*192*2);
  bf16*   acawt = (bf16*)  give((size_t)192*192*2);
  double* gw    = (double*)give((size_t)1920*8);
  double* S12   = (double*)give((size_t)20*8);

  if (off > ws_size){
    k_sentinel<<<(out_size+255)/256,256,0,stream>>>(out, out_size, (float)(ws_size>>20));
    return;
  }

  bf16*  qkv  = (bf16*)qkv_r;
  bf16*  xc   = (bf16*)qkv_r;                  // alias: qkv dead after k_acattn
  bf16*  sv   = (bf16*)(qkv_r + XC_BYTES);     // alias: spans qkv-tail + xn + sim
  bf16*  xn   = (bf16*)xn_r;
  bf16*  atmp = (bf16*)xn_r;                   // alias: xn dead between qkv-mm and LN2
  float* sim  = (float*)sim_r;

  // weight converts (tiny)
  k_wt<<<(192*576+255)/256,256,0,stream>>>(wqkv, wqkvt, 192, 576);
  k_wt<<<(192*384+255)/256,256,0,stream>>>(f1w, f1wt, 192, 384);
  k_wt<<<(448*192+255)/256,256,0,stream>>>(f2w, f2wt, 448, 192);
  k_wt<<<(192*192+255)/256,256,0,stream>>>(winw, winwt, 192, 192);
  k_wt<<<(192*192+255)/256,256,0,stream>>>(acaw, acawt, 192, 192);
  k_gw<<<1,256,0,stream>>>(n1g, n1b, wq, wqb, gw, S12);
  // Phase A: LN1 -> qkv -> window attention (init residual accumulator)
  k_ln<0><<<NT/4,256,0,stream>>>(x, nullptr, n1g, n1b, xn);
  k_mm<192,192,576,0,0><<<dim3(NT/64,9),256,0,stream>>>(xn, wqkvt, wqkvb, nullptr, qkv);
  k_rpbq<<<NHEADS*256*256/256,256,0,stream>>>(rpi, rpbt, rpbq);
  k_winattn<<<NB*64*NHEADS,256,0,stream>>>(qkv, rpbq, atmp);
  k_mm<192,192,192,0,3><<<dim3(NT/64,3),256,0,stream>>>(atmp, winwt, winb, x, xacc);
  // Dict projections + sim/argmax (f64 chain) + stable sort
  k_kn<<<4,64,0,stream>>>(td, wk, wkb, kn);
  k_v<<<(NB*64*CC)/256,256,0,stream>>>(td, wv, wvb, vbuf);
  k_tdf<<<(NB*64*DTD)/256,256,0,stream>>>(td, tdw, tdbb, tdf);
  k_sim<<<NT/32,256,0,stream>>>(x, gw, S12, kn, atds, sim, tkid);
  k_hist<<<NB*64,256,0,stream>>>(tkid, chist);
  k_scan<<<NB,64,0,stream>>>(chist, coff, bstart);
  k_place<<<NB*64,256,0,stream>>>(tkid, coff, bstart, sidx);
  // Grouped attention (last qkv reader), then residual adds
  k_acattn<<<NB*128*NHEADS,256,0,stream>>>(qkv, sidx, atmp);
  k_mm<192,192,192,0,4><<<dim3(NT/64,3),256,0,stream>>>(atmp, acawt, acab, sidx, xacc);
  k_xatd<<<NT/8,64,0,stream>>>(sim, vbuf, xacc);
  // Phase B: FFN (xc aliases qkv; sv aliases dead regions)
  k_tdgather<<<NT*64/256,256,0,stream>>>(tdf, tkid, xc);
  k_ln<1><<<NT/4,256,0,stream>>>(nullptr, xacc, n2g, n2b, xn);
  k_mm<192,192,448,1,0><<<dim3(NT/64,6),256,0,stream>>>(xn, f1wt, f1b, nullptr, xc);
  k_dw<<<NT*56/4/256,256,0,stream>>>(xc, dww, dwb, sv);
  k_mm<448,64,192,0,2><<<dim3(NT/64,3),256,0,stream>>>(sv, f2wt, f2bb, xacc, out);
}